// Round 12
// baseline (196.212 us; speedup 1.0000x reference)
//
#include <hip/hip_runtime.h>

#define RSQRT_D 0.08838834764831843f

// =====================================================================
// K1: blocks 0..511  -> map/polyline encoder (one block per (b,m))
//     blocks 512..767 -> agent MLP, 256 thr = 2 halves x 4 rows
// (unchanged from round 10)
// =====================================================================
__global__ __launch_bounds__(256) void kAB_front(
    const float* __restrict__ poly, const float* __restrict__ pmask,
    const int* __restrict__ ptype, const int* __restrict__ ptl, const int* __restrict__ proute,
    const float* __restrict__ pm_w1, const float* __restrict__ pm_b1,
    const float* __restrict__ pm_w2, const float* __restrict__ pm_b2,
    const float* __restrict__ type_emb, const float* __restrict__ tl_emb, const float* __restrict__ route_emb,
    const float* __restrict__ mo_w1, const float* __restrict__ mo_b1,
    const float* __restrict__ mo_w2, const float* __restrict__ mo_b2,
    const float* __restrict__ astate, const float* __restrict__ amask,
    const float* __restrict__ ae_w1, const float* __restrict__ ae_b1,
    const float* __restrict__ ae_w2, const float* __restrict__ ae_b2,
    const float* __restrict__ ae_w3, const float* __restrict__ ae_b3,
    float* __restrict__ map_node, float* __restrict__ map_nodeT, float* __restrict__ center,
    float* __restrict__ a_emb, float* __restrict__ aT, float* __restrict__ posT)
{
    int tid = threadIdx.x;
    if (blockIdx.x < 512) {
        int bm = blockIdx.x;
        int b = bm >> 8, m = bm & 255;
        int h = tid & 127, rw = tid >> 7;
        __shared__ float xch[2][128];
        __shared__ __align__(16) float hvs[128];
        __shared__ __align__(16) float g2[128];

        const float* pp = poly + bm*40 + rw*20;
        float xs[10], ys[10];
        #pragma unroll
        for (int u = 0; u < 10; ++u) { xs[u] = pp[2*u]; ys[u] = pp[2*u+1]; }
        float acc[10];
        #pragma unroll
        for (int u = 0; u < 10; ++u) acc[u] = 0.f;
        #pragma unroll 4
        for (int k = 0; k < 128; ++k) {
            float w2v = pm_w2[k*128 + h];
            float wx = pm_w1[k], wy = pm_w1[128+k], bb = pm_b1[k];
            #pragma unroll
            for (int u = 0; u < 10; ++u) {
                float h1 = fmaxf(fmaf(wx, xs[u], fmaf(wy, ys[u], bb)), 0.f);
                acc[u] = fmaf(h1, w2v, acc[u]);
            }
        }
        float mx = acc[0];
        #pragma unroll
        for (int u = 1; u < 10; ++u) mx = fmaxf(mx, acc[u]);
        xch[rw][h] = mx;
        __syncthreads();
        if (rw == 0) {
            float v = fmaxf(fmaxf(mx, xch[1][h]) + pm_b2[h], 0.f);
            int ti = min(max(ptype[bm],0),3);
            int si = min(max(ptl[bm],0),7);
            int ri = min(max(proute[bm],0),1);
            hvs[h] = v + type_emb[ti*128+h] + tl_emb[si*128+h] + route_emb[ri*128+h];
        }
        __syncthreads();
        if (rw == 0) {
            float a1 = mo_b1[h];
            for (int kc = 0; kc < 32; ++kc) {
                float4 xv = *(const float4*)&hvs[kc*4];
                a1 = fmaf(xv.x, mo_w1[(kc*4+0)*128+h],
                     fmaf(xv.y, mo_w1[(kc*4+1)*128+h],
                     fmaf(xv.z, mo_w1[(kc*4+2)*128+h],
                     fmaf(xv.w, mo_w1[(kc*4+3)*128+h], a1))));
            }
            g2[h] = fmaxf(a1, 0.f);
        }
        __syncthreads();
        if (rw == 0) {
            float a2 = mo_b2[h];
            for (int kc = 0; kc < 32; ++kc) {
                float4 xv = *(const float4*)&g2[kc*4];
                a2 = fmaf(xv.x, mo_w2[(kc*4+0)*128+h],
                     fmaf(xv.y, mo_w2[(kc*4+1)*128+h],
                     fmaf(xv.z, mo_w2[(kc*4+2)*128+h],
                     fmaf(xv.w, mo_w2[(kc*4+3)*128+h], a2))));
            }
            float mk = (pmask[bm] > 0.5f) ? 1.f : 0.f;
            a2 *= mk;
            map_node[bm*128 + h] = a2;
            map_nodeT[(b*128+h)*256 + m] = a2;
        }
        if (tid == 0) {
            float sx = 0.f, sy = 0.f;
            #pragma unroll
            for (int l = 0; l < 20; ++l) { sx += poly[bm*40 + 2*l]; sy += poly[bm*40 + 2*l + 1]; }
            center[bm*2+0] = sx * 0.05f;
            center[bm*2+1] = sy * 0.05f;
        }
    } else {
        int h = tid & 127, rp = tid >> 7;
        int r0 = (blockIdx.x - 512)*8 + rp*4;
        __shared__ float f5[2][4][5];
        __shared__ __align__(16) float a1s[2][4][128];
        if (h < 20) f5[rp][h/5][h%5] = astate[(r0 + h/5)*5 + (h%5)];
        __syncthreads();
        float b1v = ae_b1[h];
        float v[4];
        {
            float w0 = ae_w1[h], w1 = ae_w1[128+h], w2 = ae_w1[256+h], w3 = ae_w1[384+h], w4 = ae_w1[512+h];
            #pragma unroll
            for (int r = 0; r < 4; ++r) {
                float a = b1v;
                a = fmaf(f5[rp][r][0], w0, a); a = fmaf(f5[rp][r][1], w1, a);
                a = fmaf(f5[rp][r][2], w2, a); a = fmaf(f5[rp][r][3], w3, a);
                a = fmaf(f5[rp][r][4], w4, a);
                v[r] = fmaxf(a, 0.f);
            }
        }
        #pragma unroll
        for (int r = 0; r < 4; ++r) a1s[rp][r][h] = v[r];
        __syncthreads();
        {
            float b2v = ae_b2[h];
            float a0 = b2v, a1 = b2v, a2 = b2v, a3 = b2v;
            for (int kc = 0; kc < 32; ++kc) {
                float4 x0 = *(const float4*)&a1s[rp][0][kc*4];
                float4 x1 = *(const float4*)&a1s[rp][1][kc*4];
                float4 x2 = *(const float4*)&a1s[rp][2][kc*4];
                float4 x3 = *(const float4*)&a1s[rp][3][kc*4];
                float w0 = ae_w2[(kc*4+0)*128+h], w1 = ae_w2[(kc*4+1)*128+h];
                float w2 = ae_w2[(kc*4+2)*128+h], w3 = ae_w2[(kc*4+3)*128+h];
                a0 = fmaf(x0.x,w0,fmaf(x0.y,w1,fmaf(x0.z,w2,fmaf(x0.w,w3,a0))));
                a1 = fmaf(x1.x,w0,fmaf(x1.y,w1,fmaf(x1.z,w2,fmaf(x1.w,w3,a1))));
                a2 = fmaf(x2.x,w0,fmaf(x2.y,w1,fmaf(x2.z,w2,fmaf(x2.w,w3,a2))));
                a3 = fmaf(x3.x,w0,fmaf(x3.y,w1,fmaf(x3.z,w2,fmaf(x3.w,w3,a3))));
            }
            v[0]=fmaxf(a0,0.f); v[1]=fmaxf(a1,0.f); v[2]=fmaxf(a2,0.f); v[3]=fmaxf(a3,0.f);
        }
        __syncthreads();
        #pragma unroll
        for (int r = 0; r < 4; ++r) a1s[rp][r][h] = v[r];
        __syncthreads();
        {
            float b3v = ae_b3[h];
            float a0 = b3v, a1 = b3v, a2 = b3v, a3 = b3v;
            for (int kc = 0; kc < 32; ++kc) {
                float4 x0 = *(const float4*)&a1s[rp][0][kc*4];
                float4 x1 = *(const float4*)&a1s[rp][1][kc*4];
                float4 x2 = *(const float4*)&a1s[rp][2][kc*4];
                float4 x3 = *(const float4*)&a1s[rp][3][kc*4];
                float w0 = ae_w3[(kc*4+0)*128+h], w1 = ae_w3[(kc*4+1)*128+h];
                float w2 = ae_w3[(kc*4+2)*128+h], w3 = ae_w3[(kc*4+3)*128+h];
                a0 = fmaf(x0.x,w0,fmaf(x0.y,w1,fmaf(x0.z,w2,fmaf(x0.w,w3,a0))));
                a1 = fmaf(x1.x,w0,fmaf(x1.y,w1,fmaf(x1.z,w2,fmaf(x1.w,w3,a1))));
                a2 = fmaf(x2.x,w0,fmaf(x2.y,w1,fmaf(x2.z,w2,fmaf(x2.w,w3,a2))));
                a3 = fmaf(x3.x,w0,fmaf(x3.y,w1,fmaf(x3.z,w2,fmaf(x3.w,w3,a3))));
            }
            v[0]=a0; v[1]=a1; v[2]=a2; v[3]=a3;
        }
        #pragma unroll
        for (int r = 0; r < 4; ++r) {
            int rr = r0 + r;
            float mk = (amask[rr] > 0.5f) ? 1.f : 0.f;
            float e = v[r] * mk;
            a_emb[rr*128 + h] = e;
            int bb = rr >> 10, nn = (rr >> 5) & 31, tt = rr & 31;
            int bt = bb*32 + tt;
            aT[(bt*128 + h)*32 + nn] = e;
        }
        if (h < 20) {
            int r = h / 5, c = h % 5;
            int rr = r0 + r;
            int bb = rr >> 10, nn = (rr >> 5) & 31, tt = rr & 31;
            int bt = bb*32 + tt;
            float val;
            if      (c == 0) val = f5[rp][r][0];
            else if (c == 1) val = f5[rp][r][1];
            else if (c == 2) val = f5[rp][r][3];
            else if (c == 3) val = f5[rp][r][4];
            else             val = amask[rr];
            posT[(bt*5 + c)*32 + nn] = val;
        }
    }
}

// =====================================================================
// K2: 512-thread blocks.
//  blocks 0..511  -> map attention per quad; (m, hf) split of the two
//                    inner loops (logit is linear in the partials).
//  blocks 512..767-> neighbor logits+softmax, 8 rows/block (wave = row).
// =====================================================================
__global__ __launch_bounds__(512) void kC_attn(
    const float* __restrict__ astate, const float* __restrict__ amask,
    const float* __restrict__ pmask,
    const float* __restrict__ a_emb, const float* __restrict__ map_node,
    const float* __restrict__ map_nodeT, const float* __restrict__ center,
    const float* __restrict__ mr_w1, const float* __restrict__ mr_b1,
    const float* __restrict__ mr_w2, const float* __restrict__ mr_b2,
    const float* __restrict__ aT, const float* __restrict__ posT,
    const float* __restrict__ nr_w1, const float* __restrict__ nr_b1,
    const float* __restrict__ nr_w2, const float* __restrict__ nr_b2,
    float* __restrict__ map_ctx, float* __restrict__ p_n)
{
    int tid = threadIdx.x;
    int lam = tid & 63, wv = tid >> 6;
    __shared__ float lgp[2][4][256];
    __shared__ float lg4[4][256];
    __shared__ __align__(16) float p4[256*4];
    __shared__ float ctxp[4][4][128];

    if (blockIdx.x < 512) {
        int r0 = blockIdx.x * 4;
        int b = r0 >> 10;
        int m = tid & 255, hf = tid >> 8;
        int h0 = hf * 64;
        // ---- partial logits: hf covers hh in [h0,h0+64) and d in [h0,h0+64) ----
        {
            float rx[4], ry[4], dd[4], dt[4], sA[4];
            float b2c = (hf == 0) ? mr_b2[0] : 0.f;
            float cx = center[(b*256+m)*2+0], cy = center[(b*256+m)*2+1];
            #pragma unroll
            for (int r = 0; r < 4; ++r) {
                float px = astate[(r0+r)*5+0], py = astate[(r0+r)*5+1];
                rx[r] = cx - px; ry[r] = cy - py;
                dd[r] = sqrtf(rx[r]*rx[r] + ry[r]*ry[r]);
                dt[r] = 0.f; sA[r] = b2c;
            }
            #pragma unroll 8
            for (int q = 0; q < 64; ++q) {
                int hh = h0 + q;
                float wa = mr_w1[hh], wb = mr_w1[128+hh], wc = mr_w1[256+hh];
                float bb = mr_b1[hh], w2 = mr_w2[hh];
                #pragma unroll
                for (int r = 0; r < 4; ++r) {
                    float t1 = fmaf(rx[r], wa, fmaf(ry[r], wb, fmaf(dd[r], wc, bb)));
                    sA[r] = fmaf(fmaxf(t1, 0.f), w2, sA[r]);
                }
            }
            const float* mT = map_nodeT + b*128*256 + m;
            #pragma unroll 8
            for (int q = 0; q < 64; ++q) {
                int d = h0 + q;
                float v = mT[d*256];
                #pragma unroll
                for (int r = 0; r < 4; ++r)
                    dt[r] = fmaf(v, a_emb[(r0+r)*128 + d], dt[r]);
            }
            #pragma unroll
            for (int r = 0; r < 4; ++r)
                lgp[hf][r][m] = fmaf(dt[r], RSQRT_D, sA[r]);
        }
        __syncthreads();
        if (hf == 0) {
            bool mk = pmask[b*256+m] > 0.5f;
            #pragma unroll
            for (int r = 0; r < 4; ++r)
                lg4[r][m] = mk ? (lgp[0][r][m] + lgp[1][r][m]) : -1e30f;
        }
        __syncthreads();
        // ---- softmax: waves 0..3, wave wv = row wv ----
        if (tid < 256) {
            float x0 = lg4[wv][lam], x1 = lg4[wv][64+lam], x2 = lg4[wv][128+lam], x3 = lg4[wv][192+lam];
            float mxv = fmaxf(fmaxf(x0,x1), fmaxf(x2,x3));
            #pragma unroll
            for (int off = 32; off; off >>= 1) mxv = fmaxf(mxv, __shfl_xor(mxv, off));
            float e0 = (x0 > -1e29f) ? expf(x0-mxv) : 0.f;
            float e1 = (x1 > -1e29f) ? expf(x1-mxv) : 0.f;
            float e2 = (x2 > -1e29f) ? expf(x2-mxv) : 0.f;
            float e3 = (x3 > -1e29f) ? expf(x3-mxv) : 0.f;
            float sm = e0+e1+e2+e3;
            #pragma unroll
            for (int off = 32; off; off >>= 1) sm += __shfl_xor(sm, off);
            float inv = 1.f / fmaxf(sm, 1e-9f);
            p4[lam*4 + wv]       = e0*inv;
            p4[(64+lam)*4 + wv]  = e1*inv;
            p4[(128+lam)*4 + wv] = e2*inv;
            p4[(192+lam)*4 + wv] = e3*inv;
        }
        __syncthreads();
        // ---- PV: thread (d = tid&127, q = tid>>7) covers m in [64q, 64q+64) ----
        {
            int d = tid & 127, q = tid >> 7;
            float ac0 = 0.f, ac1 = 0.f, ac2 = 0.f, ac3 = 0.f;
            const float* mn = map_node + (b*256 + q*64)*128 + d;
            const float4* pp = (const float4*)p4 + q*64;
            #pragma unroll 4
            for (int mm = 0; mm < 64; ++mm) {
                float4 pv = pp[mm];
                float v = mn[mm*128];
                ac0 = fmaf(pv.x, v, ac0); ac1 = fmaf(pv.y, v, ac1);
                ac2 = fmaf(pv.z, v, ac2); ac3 = fmaf(pv.w, v, ac3);
            }
            ctxp[q][0][d] = ac0; ctxp[q][1][d] = ac1;
            ctxp[q][2][d] = ac2; ctxp[q][3][d] = ac3;
        }
        __syncthreads();
        {
            int d = tid & 127, r = tid >> 7;   // 512 threads = (d, r)
            map_ctx[(r0+r)*128 + d] =
                ctxp[0][r][d] + ctxp[1][r][d] + ctxp[2][r][d] + ctxp[3][r][d];
        }
    } else {
        // ---- neighbor: 8 waves, wave = row; lane = (j, hh-half) ----
        int r = (blockIdx.x - 512)*8 + wv;
        int b = r >> 10, ii = (r >> 5) & 31, tt = r & 31;
        int bt = b*32 + tt;
        int j = lam & 31, hs = lam >> 5;
        float pxi = astate[r*5+0], pyi = astate[r*5+1], vxi = astate[r*5+3], vyi = astate[r*5+4];
        const float* pT = posT + bt*160;
        float pxj = pT[j], pyj = pT[32+j], vxj = pT[64+j], vyj = pT[96+j], mj = pT[128+j];
        float rpx = pxj-pxi, rpy = pyj-pyi, rvx = vxj-vxi, rvy = vyj-vyi;
        float ddv = sqrtf(rpx*rpx + rpy*rpy);
        const float* ei = a_emb + (size_t)r*128;
        const float* aTp = aT + (size_t)bt*4096 + j;
        float s = 0.f, dot = 0.f;
        int h0 = hs*64;
        #pragma unroll 8
        for (int q = 0; q < 64; ++q) {
            int hh = h0 + q;
            float wA = nr_w1[hh], wB = nr_w1[128+hh], wC = nr_w1[256+hh];
            float wD = nr_w1[384+hh], wE = nr_w1[512+hh];
            float bb = nr_b1[hh], w2 = nr_w2[hh];
            float t1 = fmaf(rpx, wA, fmaf(rpy, wB, fmaf(rvx, wC,
                       fmaf(rvy, wD, fmaf(ddv, wE, bb)))));
            s = fmaf(fmaxf(t1, 0.f), w2, s);
            dot = fmaf(ei[hh], aTp[hh*32], dot);
        }
        s   += __shfl_xor(s, 32);
        dot += __shfl_xor(dot, 32);
        bool vi = amask[r] > 0.5f, vj = mj > 0.5f;
        bool ok = vi && vj && (ddv <= 30.0f) && (j != ii);
        float lg = ok ? fmaf(dot, RSQRT_D, s + nr_b2[0]) : -1e30f;
        float mxv = lg;
        #pragma unroll
        for (int off = 16; off; off >>= 1) mxv = fmaxf(mxv, __shfl_xor(mxv, off));
        float e = (lg > -1e29f) ? expf(lg - mxv) : 0.f;
        float sm = e;
        #pragma unroll
        for (int off = 16; off; off >>= 1) sm += __shfl_xor(sm, off);
        if (hs == 0) p_n[r*32 + j] = e / fmaxf(sm, 1e-9f);
    }
}

// =====================================================================
// K3: neighbor ctx + output MLP (r10 kD unchanged).
// =====================================================================
__global__ __launch_bounds__(256) void kD_out(
    const float* __restrict__ amask, const float* __restrict__ a_emb,
    const float* __restrict__ map_ctx, const float* __restrict__ p_n,
    const float* __restrict__ to_w1, const float* __restrict__ to_b1,
    const float* __restrict__ to_w2, const float* __restrict__ to_b2,
    float* __restrict__ out)
{
    int r0 = blockIdx.x * 4;
    int b = r0 >> 10, t0 = r0 & 31;
    int tid = threadIdx.x;
    __shared__ __align__(16) float tau[4][384];
    __shared__ float redn[4][128];
    __shared__ __align__(16) float gpart[4][4][128];
    __shared__ __align__(16) float g1s[4][128];

    for (int q = tid; q < 512; q += 256) {
        int rr = q >> 7, d = q & 127;
        tau[rr][d]       = a_emb[(r0+rr)*128 + d];
        tau[rr][128 + d] = map_ctx[(r0+rr)*128 + d];
    }
    __syncthreads();
    {
        int d = tid & 127, hf = tid >> 7;
        float ac[4] = {0.f,0.f,0.f,0.f};
        for (int jj = 0; jj < 16; ++jj) {
            int j2 = hf*16 + jj;
            float p0 = p_n[(r0+0)*32 + j2];
            float p1 = p_n[(r0+1)*32 + j2];
            float p2 = p_n[(r0+2)*32 + j2];
            float p3 = p_n[(r0+3)*32 + j2];
            const float* ejb = a_emb + (size_t)((b*32 + j2)*32 + t0)*128 + d;
            ac[0] = fmaf(p0, ejb[0],   ac[0]);
            ac[1] = fmaf(p1, ejb[128], ac[1]);
            ac[2] = fmaf(p2, ejb[256], ac[2]);
            ac[3] = fmaf(p3, ejb[384], ac[3]);
        }
        if (hf == 1) { redn[0][d]=ac[0]; redn[1][d]=ac[1]; redn[2][d]=ac[2]; redn[3][d]=ac[3]; }
        __syncthreads();
        if (hf == 0) {
            #pragma unroll
            for (int r = 0; r < 4; ++r) tau[r][256 + d] = ac[r] + redn[r][d];
        }
    }
    __syncthreads();
    {
        int h6 = tid & 63, kq = tid >> 6;
        float aL[4] = {0.f,0.f,0.f,0.f};
        float aH[4] = {0.f,0.f,0.f,0.f};
        for (int c = 0; c < 24; ++c) {
            int k4 = kq*24 + c;
            float4 x0 = *(const float4*)&tau[0][k4*4];
            float4 x1 = *(const float4*)&tau[1][k4*4];
            float4 x2 = *(const float4*)&tau[2][k4*4];
            float4 x3 = *(const float4*)&tau[3][k4*4];
            float wl0 = to_w1[(k4*4+0)*128 + h6], wh0 = to_w1[(k4*4+0)*128 + 64+h6];
            float wl1 = to_w1[(k4*4+1)*128 + h6], wh1 = to_w1[(k4*4+1)*128 + 64+h6];
            float wl2 = to_w1[(k4*4+2)*128 + h6], wh2 = to_w1[(k4*4+2)*128 + 64+h6];
            float wl3 = to_w1[(k4*4+3)*128 + h6], wh3 = to_w1[(k4*4+3)*128 + 64+h6];
            aL[0]=fmaf(x0.x,wl0,fmaf(x0.y,wl1,fmaf(x0.z,wl2,fmaf(x0.w,wl3,aL[0]))));
            aH[0]=fmaf(x0.x,wh0,fmaf(x0.y,wh1,fmaf(x0.z,wh2,fmaf(x0.w,wh3,aH[0]))));
            aL[1]=fmaf(x1.x,wl0,fmaf(x1.y,wl1,fmaf(x1.z,wl2,fmaf(x1.w,wl3,aL[1]))));
            aH[1]=fmaf(x1.x,wh0,fmaf(x1.y,wh1,fmaf(x1.z,wh2,fmaf(x1.w,wh3,aH[1]))));
            aL[2]=fmaf(x2.x,wl0,fmaf(x2.y,wl1,fmaf(x2.z,wl2,fmaf(x2.w,wl3,aL[2]))));
            aH[2]=fmaf(x2.x,wh0,fmaf(x2.y,wh1,fmaf(x2.z,wh2,fmaf(x2.w,wh3,aH[2]))));
            aL[3]=fmaf(x3.x,wl0,fmaf(x3.y,wl1,fmaf(x3.z,wl2,fmaf(x3.w,wl3,aL[3]))));
            aH[3]=fmaf(x3.x,wh0,fmaf(x3.y,wh1,fmaf(x3.z,wh2,fmaf(x3.w,wh3,aH[3]))));
        }
        #pragma unroll
        for (int r = 0; r < 4; ++r) {
            gpart[kq][r][h6]      = aL[r];
            gpart[kq][r][64 + h6] = aH[r];
        }
    }
    __syncthreads();
    {
        int h = tid & 127, rp = tid >> 7;
        float bv = to_b1[h];
        #pragma unroll
        for (int rr = rp; rr < 4; rr += 2) {
            float s = gpart[0][rr][h] + gpart[1][rr][h] + gpart[2][rr][h] + gpart[3][rr][h];
            g1s[rr][h] = fmaxf(s + bv, 0.f);
        }
    }
    __syncthreads();
    {
        int o = tid & 63, row = tid >> 6;
        float a2 = to_b2[o];
        for (int kc = 0; kc < 32; ++kc) {
            float4 g = *(const float4*)&g1s[row][kc*4];
            a2 = fmaf(g.x, to_w2[(kc*4+0)*64 + o],
                 fmaf(g.y, to_w2[(kc*4+1)*64 + o],
                 fmaf(g.z, to_w2[(kc*4+2)*64 + o],
                 fmaf(g.w, to_w2[(kc*4+3)*64 + o], a2))));
        }
        float mk = (amask[r0+row] > 0.5f) ? 1.f : 0.f;
        out[(r0+row)*64 + o] = a2 * mk;
    }
}

extern "C" void kernel_launch(void* const* d_in, const int* in_sizes, int n_in,
                              void* d_out, int out_size, void* d_ws, size_t ws_size,
                              hipStream_t stream) {
    const float* agents_state  = (const float*)d_in[0];
    const float* agents_mask   = (const float*)d_in[1];
    const float* map_polylines = (const float*)d_in[2];
    const float* map_poly_mask = (const float*)d_in[3];
    const int*   map_poly_type = (const int*)d_in[4];
    const int*   map_tl_status = (const int*)d_in[5];
    const int*   map_on_route  = (const int*)d_in[6];
    const float* pm_w1 = (const float*)d_in[7];
    const float* pm_b1 = (const float*)d_in[8];
    const float* pm_w2 = (const float*)d_in[9];
    const float* pm_b2 = (const float*)d_in[10];
    const float* type_emb  = (const float*)d_in[11];
    const float* tl_emb    = (const float*)d_in[12];
    const float* route_emb = (const float*)d_in[13];
    const float* mo_w1 = (const float*)d_in[14];
    const float* mo_b1 = (const float*)d_in[15];
    const float* mo_w2 = (const float*)d_in[16];
    const float* mo_b2 = (const float*)d_in[17];
    const float* ae_w1 = (const float*)d_in[18];
    const float* ae_b1 = (const float*)d_in[19];
    const float* ae_w2 = (const float*)d_in[20];
    const float* ae_b2 = (const float*)d_in[21];
    const float* ae_w3 = (const float*)d_in[22];
    const float* ae_b3 = (const float*)d_in[23];
    const float* mr_w1 = (const float*)d_in[24];
    const float* mr_b1 = (const float*)d_in[25];
    const float* mr_w2 = (const float*)d_in[26];
    const float* mr_b2 = (const float*)d_in[27];
    const float* nr_w1 = (const float*)d_in[28];
    const float* nr_b1 = (const float*)d_in[29];
    const float* nr_w2 = (const float*)d_in[30];
    const float* nr_b2 = (const float*)d_in[31];
    const float* to_w1 = (const float*)d_in[32];
    const float* to_b1 = (const float*)d_in[33];
    const float* to_w2 = (const float*)d_in[34];
    const float* to_b2 = (const float*)d_in[35];

    float* ws = (float*)d_ws;
    float* map_node  = ws;                 // 65536
    float* map_nodeT = ws + 65536;         // 65536
    float* center    = ws + 131072;        // 1024
    float* a_emb     = ws + 132096;        // 262144
    float* aT        = ws + 394240;        // 262144
    float* posT      = ws + 656384;        // 10240
    float* map_ctx   = ws + 666624;        // 262144
    float* p_n       = ws + 928768;        // 65536

    float* out = (float*)d_out;

    kAB_front<<<768, 256, 0, stream>>>(map_polylines, map_poly_mask,
        map_poly_type, map_tl_status, map_on_route,
        pm_w1, pm_b1, pm_w2, pm_b2, type_emb, tl_emb, route_emb,
        mo_w1, mo_b1, mo_w2, mo_b2,
        agents_state, agents_mask,
        ae_w1, ae_b1, ae_w2, ae_b2, ae_w3, ae_b3,
        map_node, map_nodeT, center, a_emb, aT, posT);

    kC_attn<<<768, 512, 0, stream>>>(agents_state, agents_mask, map_poly_mask,
        a_emb, map_node, map_nodeT, center,
        mr_w1, mr_b1, mr_w2, mr_b2,
        aT, posT,
        nr_w1, nr_b1, nr_w2, nr_b2,
        map_ctx, p_n);

    kD_out<<<512, 256, 0, stream>>>(agents_mask, a_emb, map_ctx, p_n,
        to_w1, to_b1, to_w2, to_b2, out);
}

// Round 13
// 190.337 us; speedup vs baseline: 1.0309x; 1.0309x over previous
//
#include <hip/hip_runtime.h>

#define RSQRT_D 0.08838834764831843f

// =====================================================================
// kAB: blocks 0..511  -> map/polyline encoder (one block per (b,m))
//      blocks 512..767 -> agent MLP, 256 thr = 2 halves x 4 rows (8 rows/block)
// =====================================================================
__global__ __launch_bounds__(256) void kAB_front(
    const float* __restrict__ poly, const float* __restrict__ pmask,
    const int* __restrict__ ptype, const int* __restrict__ ptl, const int* __restrict__ proute,
    const float* __restrict__ pm_w1, const float* __restrict__ pm_b1,
    const float* __restrict__ pm_w2, const float* __restrict__ pm_b2,
    const float* __restrict__ type_emb, const float* __restrict__ tl_emb, const float* __restrict__ route_emb,
    const float* __restrict__ mo_w1, const float* __restrict__ mo_b1,
    const float* __restrict__ mo_w2, const float* __restrict__ mo_b2,
    const float* __restrict__ astate, const float* __restrict__ amask,
    const float* __restrict__ ae_w1, const float* __restrict__ ae_b1,
    const float* __restrict__ ae_w2, const float* __restrict__ ae_b2,
    const float* __restrict__ ae_w3, const float* __restrict__ ae_b3,
    float* __restrict__ map_node, float* __restrict__ map_nodeT, float* __restrict__ center,
    float* __restrict__ a_emb, float* __restrict__ aT, float* __restrict__ posT)
{
    int tid = threadIdx.x;
    if (blockIdx.x < 512) {
        int bm = blockIdx.x;
        int b = bm >> 8, m = bm & 255;
        int h = tid & 127, rw = tid >> 7;
        __shared__ float xch[2][128];
        __shared__ __align__(16) float hvs[128];
        __shared__ __align__(16) float g2[128];

        const float* pp = poly + bm*40 + rw*20;
        float xs[10], ys[10];
        #pragma unroll
        for (int u = 0; u < 10; ++u) { xs[u] = pp[2*u]; ys[u] = pp[2*u+1]; }
        float acc[10];
        #pragma unroll
        for (int u = 0; u < 10; ++u) acc[u] = 0.f;
        #pragma unroll 4
        for (int k = 0; k < 128; ++k) {
            float w2v = pm_w2[k*128 + h];
            float wx = pm_w1[k], wy = pm_w1[128+k], bb = pm_b1[k];
            #pragma unroll
            for (int u = 0; u < 10; ++u) {
                float h1 = fmaxf(fmaf(wx, xs[u], fmaf(wy, ys[u], bb)), 0.f);
                acc[u] = fmaf(h1, w2v, acc[u]);
            }
        }
        float mx = acc[0];
        #pragma unroll
        for (int u = 1; u < 10; ++u) mx = fmaxf(mx, acc[u]);
        xch[rw][h] = mx;
        __syncthreads();
        if (rw == 0) {
            float v = fmaxf(fmaxf(mx, xch[1][h]) + pm_b2[h], 0.f);
            int ti = min(max(ptype[bm],0),3);
            int si = min(max(ptl[bm],0),7);
            int ri = min(max(proute[bm],0),1);
            hvs[h] = v + type_emb[ti*128+h] + tl_emb[si*128+h] + route_emb[ri*128+h];
        }
        __syncthreads();
        if (rw == 0) {
            float a1 = mo_b1[h];
            for (int kc = 0; kc < 32; ++kc) {
                float4 xv = *(const float4*)&hvs[kc*4];
                a1 = fmaf(xv.x, mo_w1[(kc*4+0)*128+h],
                     fmaf(xv.y, mo_w1[(kc*4+1)*128+h],
                     fmaf(xv.z, mo_w1[(kc*4+2)*128+h],
                     fmaf(xv.w, mo_w1[(kc*4+3)*128+h], a1))));
            }
            g2[h] = fmaxf(a1, 0.f);
        }
        __syncthreads();
        if (rw == 0) {
            float a2 = mo_b2[h];
            for (int kc = 0; kc < 32; ++kc) {
                float4 xv = *(const float4*)&g2[kc*4];
                a2 = fmaf(xv.x, mo_w2[(kc*4+0)*128+h],
                     fmaf(xv.y, mo_w2[(kc*4+1)*128+h],
                     fmaf(xv.z, mo_w2[(kc*4+2)*128+h],
                     fmaf(xv.w, mo_w2[(kc*4+3)*128+h], a2))));
            }
            float mk = (pmask[bm] > 0.5f) ? 1.f : 0.f;
            a2 *= mk;
            map_node[bm*128 + h] = a2;
            map_nodeT[(b*128+h)*256 + m] = a2;
        }
        if (tid == 0) {
            float sx = 0.f, sy = 0.f;
            #pragma unroll
            for (int l = 0; l < 20; ++l) { sx += poly[bm*40 + 2*l]; sy += poly[bm*40 + 2*l + 1]; }
            center[bm*2+0] = sx * 0.05f;
            center[bm*2+1] = sy * 0.05f;
        }
    } else {
        int h = tid & 127, rp = tid >> 7;
        int r0 = (blockIdx.x - 512)*8 + rp*4;
        __shared__ float f5[2][4][5];
        __shared__ __align__(16) float a1s[2][4][128];
        if (h < 20) f5[rp][h/5][h%5] = astate[(r0 + h/5)*5 + (h%5)];
        __syncthreads();
        float b1v = ae_b1[h];
        float v[4];
        {
            float w0 = ae_w1[h], w1 = ae_w1[128+h], w2 = ae_w1[256+h], w3 = ae_w1[384+h], w4 = ae_w1[512+h];
            #pragma unroll
            for (int r = 0; r < 4; ++r) {
                float a = b1v;
                a = fmaf(f5[rp][r][0], w0, a); a = fmaf(f5[rp][r][1], w1, a);
                a = fmaf(f5[rp][r][2], w2, a); a = fmaf(f5[rp][r][3], w3, a);
                a = fmaf(f5[rp][r][4], w4, a);
                v[r] = fmaxf(a, 0.f);
            }
        }
        #pragma unroll
        for (int r = 0; r < 4; ++r) a1s[rp][r][h] = v[r];
        __syncthreads();
        {
            float b2v = ae_b2[h];
            float a0 = b2v, a1 = b2v, a2 = b2v, a3 = b2v;
            for (int kc = 0; kc < 32; ++kc) {
                float4 x0 = *(const float4*)&a1s[rp][0][kc*4];
                float4 x1 = *(const float4*)&a1s[rp][1][kc*4];
                float4 x2 = *(const float4*)&a1s[rp][2][kc*4];
                float4 x3 = *(const float4*)&a1s[rp][3][kc*4];
                float w0 = ae_w2[(kc*4+0)*128+h], w1 = ae_w2[(kc*4+1)*128+h];
                float w2 = ae_w2[(kc*4+2)*128+h], w3 = ae_w2[(kc*4+3)*128+h];
                a0 = fmaf(x0.x,w0,fmaf(x0.y,w1,fmaf(x0.z,w2,fmaf(x0.w,w3,a0))));
                a1 = fmaf(x1.x,w0,fmaf(x1.y,w1,fmaf(x1.z,w2,fmaf(x1.w,w3,a1))));
                a2 = fmaf(x2.x,w0,fmaf(x2.y,w1,fmaf(x2.z,w2,fmaf(x2.w,w3,a2))));
                a3 = fmaf(x3.x,w0,fmaf(x3.y,w1,fmaf(x3.z,w2,fmaf(x3.w,w3,a3))));
            }
            v[0]=fmaxf(a0,0.f); v[1]=fmaxf(a1,0.f); v[2]=fmaxf(a2,0.f); v[3]=fmaxf(a3,0.f);
        }
        __syncthreads();
        #pragma unroll
        for (int r = 0; r < 4; ++r) a1s[rp][r][h] = v[r];
        __syncthreads();
        {
            float b3v = ae_b3[h];
            float a0 = b3v, a1 = b3v, a2 = b3v, a3 = b3v;
            for (int kc = 0; kc < 32; ++kc) {
                float4 x0 = *(const float4*)&a1s[rp][0][kc*4];
                float4 x1 = *(const float4*)&a1s[rp][1][kc*4];
                float4 x2 = *(const float4*)&a1s[rp][2][kc*4];
                float4 x3 = *(const float4*)&a1s[rp][3][kc*4];
                float w0 = ae_w3[(kc*4+0)*128+h], w1 = ae_w3[(kc*4+1)*128+h];
                float w2 = ae_w3[(kc*4+2)*128+h], w3 = ae_w3[(kc*4+3)*128+h];
                a0 = fmaf(x0.x,w0,fmaf(x0.y,w1,fmaf(x0.z,w2,fmaf(x0.w,w3,a0))));
                a1 = fmaf(x1.x,w0,fmaf(x1.y,w1,fmaf(x1.z,w2,fmaf(x1.w,w3,a1))));
                a2 = fmaf(x2.x,w0,fmaf(x2.y,w1,fmaf(x2.z,w2,fmaf(x2.w,w3,a2))));
                a3 = fmaf(x3.x,w0,fmaf(x3.y,w1,fmaf(x3.z,w2,fmaf(x3.w,w3,a3))));
            }
            v[0]=a0; v[1]=a1; v[2]=a2; v[3]=a3;
        }
        #pragma unroll
        for (int r = 0; r < 4; ++r) {
            int rr = r0 + r;
            float mk = (amask[rr] > 0.5f) ? 1.f : 0.f;
            float e = v[r] * mk;
            a_emb[rr*128 + h] = e;
            int bb = rr >> 10, nn = (rr >> 5) & 31, tt = rr & 31;
            int bt = bb*32 + tt;
            aT[(bt*128 + h)*32 + nn] = e;
        }
        if (h < 20) {
            int r = h / 5, c = h % 5;
            int rr = r0 + r;
            int bb = rr >> 10, nn = (rr >> 5) & 31, tt = rr & 31;
            int bt = bb*32 + tt;
            float val;
            if      (c == 0) val = f5[rp][r][0];
            else if (c == 1) val = f5[rp][r][1];
            else if (c == 2) val = f5[rp][r][3];
            else if (c == 3) val = f5[rp][r][4];
            else             val = amask[rr];
            posT[(bt*5 + c)*32 + nn] = val;
        }
    }
}

// =====================================================================
// kC: blocks 0..511   -> map attention (logits+softmax+PV), 4 rows/block
//     blocks 512..1023-> neighbor logits+softmax; wave = row, lane = (j, hh-half)
// =====================================================================
__global__ __launch_bounds__(256) void kC_attn(
    const float* __restrict__ astate, const float* __restrict__ amask,
    const float* __restrict__ pmask,
    const float* __restrict__ a_emb, const float* __restrict__ map_node,
    const float* __restrict__ map_nodeT, const float* __restrict__ center,
    const float* __restrict__ mr_w1, const float* __restrict__ mr_b1,
    const float* __restrict__ mr_w2, const float* __restrict__ mr_b2,
    const float* __restrict__ aT, const float* __restrict__ posT,
    const float* __restrict__ nr_w1, const float* __restrict__ nr_b1,
    const float* __restrict__ nr_w2, const float* __restrict__ nr_b2,
    float* __restrict__ map_ctx, float* __restrict__ p_n)
{
    int tid = threadIdx.x;
    int lam = tid & 63, wv = tid >> 6;
    __shared__ float lg4[4][256];
    __shared__ __align__(16) float p4[256*4];
    __shared__ float ctxp[4][128];

    if (blockIdx.x < 512) {
        int r0 = blockIdx.x * 4;
        int b = r0 >> 10;
        int m = tid;
        float rx[4], ry[4], dd[4], dt[4], sA[4];
        float b2c = mr_b2[0];
        float cx = center[(b*256+m)*2+0], cy = center[(b*256+m)*2+1];
        #pragma unroll
        for (int r = 0; r < 4; ++r) {
            float px = astate[(r0+r)*5+0], py = astate[(r0+r)*5+1];
            rx[r] = cx - px; ry[r] = cy - py;
            dd[r] = sqrtf(rx[r]*rx[r] + ry[r]*ry[r]);
            dt[r] = 0.f; sA[r] = b2c;
        }
        #pragma unroll 8
        for (int hh = 0; hh < 128; ++hh) {
            float wa = mr_w1[hh], wb = mr_w1[128+hh], wc = mr_w1[256+hh];
            float bb = mr_b1[hh], w2 = mr_w2[hh];
            #pragma unroll
            for (int r = 0; r < 4; ++r) {
                float t1 = fmaf(rx[r], wa, fmaf(ry[r], wb, fmaf(dd[r], wc, bb)));
                sA[r] = fmaf(fmaxf(t1, 0.f), w2, sA[r]);
            }
        }
        const float* mT = map_nodeT + b*128*256 + m;
        #pragma unroll 8
        for (int d = 0; d < 128; ++d) {
            float v = mT[d*256];
            #pragma unroll
            for (int r = 0; r < 4; ++r)
                dt[r] = fmaf(v, a_emb[(r0+r)*128 + d], dt[r]);
        }
        bool mk = pmask[b*256+m] > 0.5f;
        #pragma unroll
        for (int r = 0; r < 4; ++r)
            lg4[r][m] = mk ? fmaf(dt[r], RSQRT_D, sA[r]) : -1e30f;
        __syncthreads();
        {
            float x0 = lg4[wv][lam], x1 = lg4[wv][64+lam], x2 = lg4[wv][128+lam], x3 = lg4[wv][192+lam];
            float mxv = fmaxf(fmaxf(x0,x1), fmaxf(x2,x3));
            #pragma unroll
            for (int off = 32; off; off >>= 1) mxv = fmaxf(mxv, __shfl_xor(mxv, off));
            float e0 = (x0 > -1e29f) ? expf(x0-mxv) : 0.f;
            float e1 = (x1 > -1e29f) ? expf(x1-mxv) : 0.f;
            float e2 = (x2 > -1e29f) ? expf(x2-mxv) : 0.f;
            float e3 = (x3 > -1e29f) ? expf(x3-mxv) : 0.f;
            float sm = e0+e1+e2+e3;
            #pragma unroll
            for (int off = 32; off; off >>= 1) sm += __shfl_xor(sm, off);
            float inv = 1.f / fmaxf(sm, 1e-9f);
            p4[lam*4 + wv]       = e0*inv;
            p4[(64+lam)*4 + wv]  = e1*inv;
            p4[(128+lam)*4 + wv] = e2*inv;
            p4[(192+lam)*4 + wv] = e3*inv;
        }
        __syncthreads();
        {
            int d = tid & 127, hf = tid >> 7;
            float ac0 = 0.f, ac1 = 0.f, ac2 = 0.f, ac3 = 0.f;
            const float* mn = map_node + (b*256 + hf*128)*128 + d;
            const float4* pp = (const float4*)p4 + hf*128;
            #pragma unroll 4
            for (int mm = 0; mm < 128; ++mm) {
                float4 pv = pp[mm];
                float v = mn[mm*128];
                ac0 = fmaf(pv.x, v, ac0); ac1 = fmaf(pv.y, v, ac1);
                ac2 = fmaf(pv.z, v, ac2); ac3 = fmaf(pv.w, v, ac3);
            }
            if (hf == 1) { ctxp[0][d]=ac0; ctxp[1][d]=ac1; ctxp[2][d]=ac2; ctxp[3][d]=ac3; }
            __syncthreads();
            if (hf == 0) {
                map_ctx[(r0+0)*128+d] = ac0 + ctxp[0][d];
                map_ctx[(r0+1)*128+d] = ac1 + ctxp[1][d];
                map_ctx[(r0+2)*128+d] = ac2 + ctxp[2][d];
                map_ctx[(r0+3)*128+d] = ac3 + ctxp[3][d];
            }
        }
    } else {
        int r = (blockIdx.x - 512)*4 + wv;
        int b = r >> 10, ii = (r >> 5) & 31, tt = r & 31;
        int bt = b*32 + tt;
        int j = lam & 31, hs = lam >> 5;
        float pxi = astate[r*5+0], pyi = astate[r*5+1], vxi = astate[r*5+3], vyi = astate[r*5+4];
        const float* pT = posT + bt*160;
        float pxj = pT[j], pyj = pT[32+j], vxj = pT[64+j], vyj = pT[96+j], mj = pT[128+j];
        float rpx = pxj-pxi, rpy = pyj-pyi, rvx = vxj-vxi, rvy = vyj-vyi;
        float ddv = sqrtf(rpx*rpx + rpy*rpy);
        const float* ei = a_emb + (size_t)r*128;
        const float* aTp = aT + (size_t)bt*4096 + j;
        float s = 0.f, dot = 0.f;
        int h0 = hs*64;
        #pragma unroll 8
        for (int q = 0; q < 64; ++q) {
            int hh = h0 + q;
            float wA = nr_w1[hh], wB = nr_w1[128+hh], wC = nr_w1[256+hh];
            float wD = nr_w1[384+hh], wE = nr_w1[512+hh];
            float bb = nr_b1[hh], w2 = nr_w2[hh];
            float t1 = fmaf(rpx, wA, fmaf(rpy, wB, fmaf(rvx, wC,
                       fmaf(rvy, wD, fmaf(ddv, wE, bb)))));
            s = fmaf(fmaxf(t1, 0.f), w2, s);
            dot = fmaf(ei[hh], aTp[hh*32], dot);
        }
        s   += __shfl_xor(s, 32);
        dot += __shfl_xor(dot, 32);
        bool vi = amask[r] > 0.5f, vj = mj > 0.5f;
        bool ok = vi && vj && (ddv <= 30.0f) && (j != ii);
        float lg = ok ? fmaf(dot, RSQRT_D, s + nr_b2[0]) : -1e30f;
        float mxv = lg;
        #pragma unroll
        for (int off = 16; off; off >>= 1) mxv = fmaxf(mxv, __shfl_xor(mxv, off));
        float e = (lg > -1e29f) ? expf(lg - mxv) : 0.f;
        float sm = e;
        #pragma unroll
        for (int off = 16; off; off >>= 1) sm += __shfl_xor(sm, off);
        if (hs == 0) p_n[r*32 + j] = e / fmaxf(sm, 1e-9f);
    }
}

// =====================================================================
// kD: neighbor ctx + output MLP.
// =====================================================================
__global__ __launch_bounds__(256) void kD_out(
    const float* __restrict__ amask, const float* __restrict__ a_emb,
    const float* __restrict__ map_ctx, const float* __restrict__ p_n,
    const float* __restrict__ to_w1, const float* __restrict__ to_b1,
    const float* __restrict__ to_w2, const float* __restrict__ to_b2,
    float* __restrict__ out)
{
    int r0 = blockIdx.x * 4;
    int b = r0 >> 10, t0 = r0 & 31;
    int tid = threadIdx.x;
    __shared__ __align__(16) float tau[4][384];
    __shared__ float redn[4][128];
    __shared__ __align__(16) float gpart[4][4][128];
    __shared__ __align__(16) float g1s[4][128];

    for (int q = tid; q < 512; q += 256) {
        int rr = q >> 7, d = q & 127;
        tau[rr][d]       = a_emb[(r0+rr)*128 + d];
        tau[rr][128 + d] = map_ctx[(r0+rr)*128 + d];
    }
    __syncthreads();
    {
        int d = tid & 127, hf = tid >> 7;
        float ac[4] = {0.f,0.f,0.f,0.f};
        for (int jj = 0; jj < 16; ++jj) {
            int j2 = hf*16 + jj;
            float p0 = p_n[(r0+0)*32 + j2];
            float p1 = p_n[(r0+1)*32 + j2];
            float p2 = p_n[(r0+2)*32 + j2];
            float p3 = p_n[(r0+3)*32 + j2];
            const float* ejb = a_emb + (size_t)((b*32 + j2)*32 + t0)*128 + d;
            ac[0] = fmaf(p0, ejb[0],   ac[0]);
            ac[1] = fmaf(p1, ejb[128], ac[1]);
            ac[2] = fmaf(p2, ejb[256], ac[2]);
            ac[3] = fmaf(p3, ejb[384], ac[3]);
        }
        if (hf == 1) { redn[0][d]=ac[0]; redn[1][d]=ac[1]; redn[2][d]=ac[2]; redn[3][d]=ac[3]; }
        __syncthreads();
        if (hf == 0) {
            #pragma unroll
            for (int r = 0; r < 4; ++r) tau[r][256 + d] = ac[r] + redn[r][d];
        }
    }
    __syncthreads();
    {
        int h6 = tid & 63, kq = tid >> 6;
        float aL[4] = {0.f,0.f,0.f,0.f};
        float aH[4] = {0.f,0.f,0.f,0.f};
        for (int c = 0; c < 24; ++c) {
            int k4 = kq*24 + c;
            float4 x0 = *(const float4*)&tau[0][k4*4];
            float4 x1 = *(const float4*)&tau[1][k4*4];
            float4 x2 = *(const float4*)&tau[2][k4*4];
            float4 x3 = *(const float4*)&tau[3][k4*4];
            float wl0 = to_w1[(k4*4+0)*128 + h6], wh0 = to_w1[(k4*4+0)*128 + 64+h6];
            float wl1 = to_w1[(k4*4+1)*128 + h6], wh1 = to_w1[(k4*4+1)*128 + 64+h6];
            float wl2 = to_w1[(k4*4+2)*128 + h6], wh2 = to_w1[(k4*4+2)*128 + 64+h6];
            float wl3 = to_w1[(k4*4+3)*128 + h6], wh3 = to_w1[(k4*4+3)*128 + 64+h6];
            aL[0]=fmaf(x0.x,wl0,fmaf(x0.y,wl1,fmaf(x0.z,wl2,fmaf(x0.w,wl3,aL[0]))));
            aH[0]=fmaf(x0.x,wh0,fmaf(x0.y,wh1,fmaf(x0.z,wh2,fmaf(x0.w,wh3,aH[0]))));
            aL[1]=fmaf(x1.x,wl0,fmaf(x1.y,wl1,fmaf(x1.z,wl2,fmaf(x1.w,wl3,aL[1]))));
            aH[1]=fmaf(x1.x,wh0,fmaf(x1.y,wh1,fmaf(x1.z,wh2,fmaf(x1.w,wh3,aH[1]))));
            aL[2]=fmaf(x2.x,wl0,fmaf(x2.y,wl1,fmaf(x2.z,wl2,fmaf(x2.w,wl3,aL[2]))));
            aH[2]=fmaf(x2.x,wh0,fmaf(x2.y,wh1,fmaf(x2.z,wh2,fmaf(x2.w,wh3,aH[2]))));
            aL[3]=fmaf(x3.x,wl0,fmaf(x3.y,wl1,fmaf(x3.z,wl2,fmaf(x3.w,wl3,aL[3]))));
            aH[3]=fmaf(x3.x,wh0,fmaf(x3.y,wh1,fmaf(x3.z,wh2,fmaf(x3.w,wh3,aH[3]))));
        }
        #pragma unroll
        for (int r = 0; r < 4; ++r) {
            gpart[kq][r][h6]      = aL[r];
            gpart[kq][r][64 + h6] = aH[r];
        }
    }
    __syncthreads();
    {
        int h = tid & 127, rp = tid >> 7;
        float bv = to_b1[h];
        #pragma unroll
        for (int rr = rp; rr < 4; rr += 2) {
            float s = gpart[0][rr][h] + gpart[1][rr][h] + gpart[2][rr][h] + gpart[3][rr][h];
            g1s[rr][h] = fmaxf(s + bv, 0.f);
        }
    }
    __syncthreads();
    {
        int o = tid & 63, row = tid >> 6;
        float a2 = to_b2[o];
        for (int kc = 0; kc < 32; ++kc) {
            float4 g = *(const float4*)&g1s[row][kc*4];
            a2 = fmaf(g.x, to_w2[(kc*4+0)*64 + o],
                 fmaf(g.y, to_w2[(kc*4+1)*64 + o],
                 fmaf(g.z, to_w2[(kc*4+2)*64 + o],
                 fmaf(g.w, to_w2[(kc*4+3)*64 + o], a2))));
        }
        float mk = (amask[r0+row] > 0.5f) ? 1.f : 0.f;
        out[(r0+row)*64 + o] = a2 * mk;
    }
}

extern "C" void kernel_launch(void* const* d_in, const int* in_sizes, int n_in,
                              void* d_out, int out_size, void* d_ws, size_t ws_size,
                              hipStream_t stream) {
    const float* agents_state  = (const float*)d_in[0];
    const float* agents_mask   = (const float*)d_in[1];
    const float* map_polylines = (const float*)d_in[2];
    const float* map_poly_mask = (const float*)d_in[3];
    const int*   map_poly_type = (const int*)d_in[4];
    const int*   map_tl_status = (const int*)d_in[5];
    const int*   map_on_route  = (const int*)d_in[6];
    const float* pm_w1 = (const float*)d_in[7];
    const float* pm_b1 = (const float*)d_in[8];
    const float* pm_w2 = (const float*)d_in[9];
    const float* pm_b2 = (const float*)d_in[10];
    const float* type_emb  = (const float*)d_in[11];
    const float* tl_emb    = (const float*)d_in[12];
    const float* route_emb = (const float*)d_in[13];
    const float* mo_w1 = (const float*)d_in[14];
    const float* mo_b1 = (const float*)d_in[15];
    const float* mo_w2 = (const float*)d_in[16];
    const float* mo_b2 = (const float*)d_in[17];
    const float* ae_w1 = (const float*)d_in[18];
    const float* ae_b1 = (const float*)d_in[19];
    const float* ae_w2 = (const float*)d_in[20];
    const float* ae_b2 = (const float*)d_in[21];
    const float* ae_w3 = (const float*)d_in[22];
    const float* ae_b3 = (const float*)d_in[23];
    const float* mr_w1 = (const float*)d_in[24];
    const float* mr_b1 = (const float*)d_in[25];
    const float* mr_w2 = (const float*)d_in[26];
    const float* mr_b2 = (const float*)d_in[27];
    const float* nr_w1 = (const float*)d_in[28];
    const float* nr_b1 = (const float*)d_in[29];
    const float* nr_w2 = (const float*)d_in[30];
    const float* nr_b2 = (const float*)d_in[31];
    const float* to_w1 = (const float*)d_in[32];
    const float* to_b1 = (const float*)d_in[33];
    const float* to_w2 = (const float*)d_in[34];
    const float* to_b2 = (const float*)d_in[35];

    float* ws = (float*)d_ws;
    float* map_node  = ws;                 // 65536
    float* map_nodeT = ws + 65536;         // 65536
    float* center    = ws + 131072;        // 1024
    float* a_emb     = ws + 132096;        // 262144
    float* aT        = ws + 394240;        // 262144
    float* posT      = ws + 656384;        // 10240
    float* map_ctx   = ws + 666624;        // 262144
    float* p_n       = ws + 928768;        // 65536

    float* out = (float*)d_out;

    kAB_front<<<768, 256, 0, stream>>>(map_polylines, map_poly_mask,
        map_poly_type, map_tl_status, map_on_route,
        pm_w1, pm_b1, pm_w2, pm_b2, type_emb, tl_emb, route_emb,
        mo_w1, mo_b1, mo_w2, mo_b2,
        agents_state, agents_mask,
        ae_w1, ae_b1, ae_w2, ae_b2, ae_w3, ae_b3,
        map_node, map_nodeT, center, a_emb, aT, posT);

    kC_attn<<<1024, 256, 0, stream>>>(agents_state, agents_mask, map_poly_mask,
        a_emb, map_node, map_nodeT, center,
        mr_w1, mr_b1, mr_w2, mr_b2,
        aT, posT,
        nr_w1, nr_b1, nr_w2, nr_b2,
        map_ctx, p_n);

    kD_out<<<512, 256, 0, stream>>>(agents_mask, a_emb, map_ctx, p_n,
        to_w1, to_b1, to_w2, to_b2, out);
}